// Round 12
// baseline (655.173 us; speedup 1.0000x reference)
//
#include <hip/hip_runtime.h>
#include <hip/hip_bf16.h>

#define N_NODES 100000
#define N_PAD   100032          // 1563 * 64
#define N_EDGES 1600000
#define DIM 128
#define N_GRAPHS 128
#define NBKT 98                 // ceil(100000/1024)
#define BSTRIDE 18432           // bucket capacity (mean 16384, +16 sigma)
#define TILES (N_PAD / 16)      // 6252 16-row tiles
#define GRID_FUSED 1563         // 4 waves/block, 1 tile/wave: 1563*4 = 6252
#define POOL_BLKS ((N_NODES + 127) / 128)   // 782
#define B1_BATCH 4096
#define B1_GRID ((N_EDGES + B1_BATCH - 1) / B1_BATCH)   // 391
#define XPREP_BLKS 12500        // N_NODES*32 / 256
#define WPREP_BLKS 384          // 6 mats x 64
#define SUMS_BLKS 64            // 16384 floats / 256

typedef unsigned short u16;
typedef unsigned int u32;
typedef __attribute__((ext_vector_type(8))) short bf16x8;
typedef __attribute__((ext_vector_type(8))) unsigned short u16x8;
typedef __attribute__((ext_vector_type(4))) float f32x4;

#define MFMA(A, B, C) __builtin_amdgcn_mfma_f32_16x16x32_bf16(A, B, C, 0, 0, 0)

__device__ __forceinline__ u16 f2bf(float x) {
    u32 u = __float_as_uint(x);
    u = (u + 0x7FFFu + ((u >> 16) & 1u)) >> 16;
    return (u16)u;
}
__device__ __forceinline__ float bf2f(u16 u) {
    return __uint_as_float(((u32)u) << 16);
}

// ===========================================================================
// bucket phase 1: append packed (dstLocal<<22 | src) to coarse buckets.
// ===========================================================================
__global__ __launch_bounds__(256) void bucket1_kernel(const int* __restrict__ src,
                                                      const int* __restrict__ dst,
                                                      u32* __restrict__ cursorB,
                                                      u32* __restrict__ pairs) {
    __shared__ int lh[NBKT];
    __shared__ u32 lbase[NBKT];
    int t = threadIdx.x;
    if (t < NBKT) lh[t] = 0;
    __syncthreads();
    int e0 = blockIdx.x * B1_BATCH;
    int d[16], s[16], rk[16];
#pragma unroll
    for (int k = 0; k < 16; ++k) {
        int e = e0 + t + k * 256;
        if (e < N_EDGES) {
            d[k] = dst[e];
            s[k] = src[e];
            rk[k] = atomicAdd(&lh[d[k] >> 10], 1);
        }
    }
    __syncthreads();
    if (t < NBKT) lbase[t] = atomicAdd(&cursorB[t], (u32)lh[t]) + (u32)(t * BSTRIDE);
    __syncthreads();
#pragma unroll
    for (int k = 0; k < 16; ++k) {
        int e = e0 + t + k * 256;
        if (e < N_EDGES) {
            u32 pos = lbase[d[k] >> 10] + (u32)rk[k];
            pairs[pos] = ((u32)(d[k] & 1023) << 22) | (u32)s[k];
        }
    }
}

// ===========================================================================
// bucket phase 2: per-bucket hist + scan -> row_ptr, then scatter into csr.
// ===========================================================================
__global__ __launch_bounds__(1024) void bucket2_kernel(const u32* __restrict__ cursorB,
                                                       const u32* __restrict__ pairs,
                                                       int* __restrict__ row_ptr,
                                                       int* __restrict__ csr) {
    __shared__ int lh[1024];
    __shared__ int rc[1024];
    __shared__ int bs[128];
    int b = blockIdx.x, t = threadIdx.x;

    if (t < 128) bs[t] = (t < NBKT) ? (int)cursorB[t] : 0;
    __syncthreads();
    for (int off = 1; off < 128; off <<= 1) {
        int v = (t < 128 && t >= off) ? bs[t - off] : 0;
        __syncthreads();
        if (t < 128) bs[t] += v;
        __syncthreads();
    }
    int cnt = (int)cursorB[b];
    int bbase = (b == 0) ? 0 : bs[b - 1];

    lh[t] = 0;
    __syncthreads();
    const u32* pb = pairs + (size_t)b * BSTRIDE;
    for (int i = t; i < cnt; i += 1024) atomicAdd(&lh[__builtin_nontemporal_load(pb + i) >> 22], 1);
    __syncthreads();

    int own = lh[t];
    for (int off = 1; off < 1024; off <<= 1) {
        int v = (t >= off) ? lh[t - off] : 0;
        __syncthreads();
        lh[t] += v;
        __syncthreads();
    }
    int excl = lh[t] - own;
    int node = b * 1024 + t;
    if (node < N_NODES) row_ptr[node] = bbase + excl;
    if (b == 0 && t == 0) row_ptr[N_NODES] = N_EDGES;
    rc[t] = bbase + excl;
    __syncthreads();

    for (int i = t; i < cnt; i += 1024) {
        u32 p = __builtin_nontemporal_load(pb + i);
        int pos = atomicAdd(&rc[p >> 22], 1);
        csr[pos] = (int)(p & 0x3FFFFFu);
    }
}

// ===========================================================================
// merged prep: x -> ROW-MAJOR bf16 plane (slice-major reverted), W planes,
// sums zero. One launch.
// ===========================================================================
struct WPrepArgs {
    const float* w[6];
    u16* buf[6];
};
__global__ __launch_bounds__(256) void prep_kernel(const float* __restrict__ x,
                                                   u16* __restrict__ hb,
                                                   WPrepArgs p,
                                                   float* __restrict__ sums) {
    int b = blockIdx.x, t = threadIdx.x;
    if (b < XPREP_BLKS) {
        int i = b * 256 + t;
        if (i < N_NODES * 32) {
            float4 v = ((const float4*)x)[i];
            ushort4 o;
            o.x = f2bf(v.x); o.y = f2bf(v.y); o.z = f2bf(v.z); o.w = f2bf(v.w);
            ((ushort4*)hb)[i] = o;
        }
    } else if (b < XPREP_BLKS + WPREP_BLKS) {
        int bb = b - XPREP_BLKS;
        int m = bb >> 6;
        int idx = (bb & 63) * 256 + t;      // n*128 + k
        int n = idx >> 7, k = idx & 127;
        float v = p.w[m][k * 128 + n];
        u16 hi = f2bf(v);
        p.buf[m][idx] = hi;
        p.buf[m][idx + 16384] = f2bf(v - bf2f(hi));
    } else {
        int i = (b - XPREP_BLKS - WPREP_BLKS) * 256 + t;
        if (i < N_GRAPHS * DIM) sums[i] = 0.f;
    }
}

// ===========================================================================
// FUSED gin layer, BARRIER-FREE per-wave pipeline (R24).
// R18's counters: gather at full speed ~64us, then ~37us MLP with memory
// IDLE -- the block-wide __syncthreads cohort-synchronizes waves. But the
// 16-row tiles are fully independent (pass1/epi1/pass2 touch only their own
// rows). So: each WAVE owns one 16-row tile end-to-end with WAVE-PRIVATE
// LDS. No __syncthreads at all; wave-synchronous LDS (in-order DS ops)
// suffices. Waves desynchronize + block churn backfills -> gather and MFMA
// phases of different waves overlap structurally.
// Gather: 8 lanes/row (lane&7 -> 16 feats), 2x16B/edge, unroll 4 edges
// => 8 loads in flight/lane (the proven R7 depth). R23's serial-lane loop
// (1 load in flight) and slice-major layout are REVERTED.
// Per-wave LDS: A[16][HS] (gather out / aliased by Hl after frag load) +
// Hh[16][HS] = 8704B; x4 waves = 34816B/block -> 4 blocks/CU, 16 waves.
// MLP: all 8 col-tiles per wave; W frags loaded per nt (L2-hot reload,
// hidden under other waves' gathers). Same MFMA count as R18.
// ===========================================================================
#define HS 136
__global__ __launch_bounds__(256, 4) void gin_layer(const u16* __restrict__ hin,
                                                    const int* __restrict__ rp,
                                                    const int* __restrict__ csr,
                                                    const u16* __restrict__ W1,
                                                    const float* __restrict__ b1,
                                                    const u16* __restrict__ W2,
                                                    const float* __restrict__ b2,
                                                    u16* __restrict__ hout, int relu) {
    __shared__ u16 lds[4][2][16 * HS];
    int tid = threadIdx.x;
    int wave = tid >> 6, lane = tid & 63;
    u16* A  = &lds[wave][0][0];   // gather out; aliased by Hl in epilogue 1
    u16* Hh = &lds[wave][1][0];

    int tile = blockIdx.x * 4 + wave;   // 0..6251, exact
    int r0 = tile * 16;

    // ================= gather: 16 rows, 2 halves of 8 rows =================
    int rh = lane >> 3;                 // row within half (0..7)
    int fl = lane & 7;                  // feature block: feats fl*16..fl*16+15
    const u16x8* h8 = (const u16x8*)hin;
#pragma unroll
    for (int h = 0; h < 2; ++h) {
        int n = r0 + h * 8 + rh;
        float a[16];
        if (n < N_NODES) {
            u16x8 s0 = h8[(size_t)n * 16 + 2 * fl];
            u16x8 s1 = h8[(size_t)n * 16 + 2 * fl + 1];
#pragma unroll
            for (int r = 0; r < 8; ++r) { a[r] = bf2f(s0[r]); a[8 + r] = bf2f(s1[r]); }
            int s = rp[n], e = rp[n + 1];
            int i = s;
            for (; i + 4 <= e; i += 4) {
                int j0 = csr[i], j1 = csr[i + 1], j2 = csr[i + 2], j3 = csr[i + 3];
                u16x8 v00 = h8[(size_t)j0 * 16 + 2 * fl], v01 = h8[(size_t)j0 * 16 + 2 * fl + 1];
                u16x8 v10 = h8[(size_t)j1 * 16 + 2 * fl], v11 = h8[(size_t)j1 * 16 + 2 * fl + 1];
                u16x8 v20 = h8[(size_t)j2 * 16 + 2 * fl], v21 = h8[(size_t)j2 * 16 + 2 * fl + 1];
                u16x8 v30 = h8[(size_t)j3 * 16 + 2 * fl], v31 = h8[(size_t)j3 * 16 + 2 * fl + 1];
#pragma unroll
                for (int r = 0; r < 8; ++r) {
                    a[r]     += (bf2f(v00[r]) + bf2f(v10[r])) + (bf2f(v20[r]) + bf2f(v30[r]));
                    a[8 + r] += (bf2f(v01[r]) + bf2f(v11[r])) + (bf2f(v21[r]) + bf2f(v31[r]));
                }
            }
            for (; i < e; ++i) {
                int j = csr[i];
                u16x8 v0 = h8[(size_t)j * 16 + 2 * fl], v1 = h8[(size_t)j * 16 + 2 * fl + 1];
#pragma unroll
                for (int r = 0; r < 8; ++r) { a[r] += bf2f(v0[r]); a[8 + r] += bf2f(v1[r]); }
            }
        } else {
#pragma unroll
            for (int r = 0; r < 16; ++r) a[r] = 0.f;
        }
        u16x8 o0, o1;
#pragma unroll
        for (int r = 0; r < 8; ++r) { o0[r] = f2bf(a[r]); o1[r] = f2bf(a[8 + r]); }
        *(u16x8*)&A[(h * 8 + rh) * HS + fl * 16] = o0;
        *(u16x8*)&A[(h * 8 + rh) * HS + fl * 16 + 8] = o1;
    }

    // ================= MLP on this wave's 16 rows (no barriers) ============
    int m16 = lane & 15, quad = lane >> 4;
    f32x4 z = {0.f, 0.f, 0.f, 0.f};

    // A frags (wave-synchronous LDS: all lanes' writes above are in-order)
    bf16x8 aH[4];
#pragma unroll
    for (int kb = 0; kb < 4; ++kb)
        aH[kb] = *(const bf16x8*)&A[m16 * HS + kb * 32 + quad * 8];

    // ---- pass 1: all 8 col-tiles, W frags loaded per nt (L2-hot) ----
    f32x4 acc[8];
#pragma unroll
    for (int nt = 0; nt < 8; ++nt) {
        int ncol = nt * 16 + m16;
        bf16x8 WH[4], WL[4];
#pragma unroll
        for (int kb = 0; kb < 4; ++kb) {
            int off = ncol * 128 + kb * 32 + quad * 8;
            WH[kb] = *(const bf16x8*)(W1 + off);
            WL[kb] = *(const bf16x8*)(W1 + off + 16384);
        }
        acc[nt] = z;
#pragma unroll
        for (int kb = 0; kb < 4; ++kb) {
            acc[nt] = MFMA(WH[kb], aH[kb], acc[nt]);
            acc[nt] = MFMA(WL[kb], aH[kb], acc[nt]);
        }
    }

    // ---- epilogue 1: bias+relu+split -> Hh + Hl(=A; aH already in regs) ----
#pragma unroll
    for (int nt = 0; nt < 8; ++nt) {
        ushort4 hv, lv;
#pragma unroll
        for (int rg = 0; rg < 4; ++rg) {
            float v = fmaxf(acc[nt][rg] + b1[nt * 16 + quad * 4 + rg], 0.f);
            u16 hi = f2bf(v);
            ((u16*)&hv)[rg] = hi;
            ((u16*)&lv)[rg] = f2bf(v - bf2f(hi));
        }
        int off = m16 * HS + nt * 16 + quad * 4;
        *(ushort4*)&Hh[off] = hv;
        *(ushort4*)&A[off]  = lv;
    }

    // ---- pass 2: W2 x H (H hi/lo), H frags loaded once ----
    bf16x8 hH[4], hL[4];
#pragma unroll
    for (int kb = 0; kb < 4; ++kb) {
        hH[kb] = *(const bf16x8*)&Hh[m16 * HS + kb * 32 + quad * 8];
        hL[kb] = *(const bf16x8*)&A[m16 * HS + kb * 32 + quad * 8];
    }
    f32x4 acc2[8];
#pragma unroll
    for (int nt = 0; nt < 8; ++nt) {
        int ncol = nt * 16 + m16;
        bf16x8 WH[4], WL[4];
#pragma unroll
        for (int kb = 0; kb < 4; ++kb) {
            int off = ncol * 128 + kb * 32 + quad * 8;
            WH[kb] = *(const bf16x8*)(W2 + off);
            WL[kb] = *(const bf16x8*)(W2 + off + 16384);
        }
        acc2[nt] = z;
#pragma unroll
        for (int kb = 0; kb < 4; ++kb) {
            acc2[nt] = MFMA(WH[kb], hH[kb], acc2[nt]);
            acc2[nt] = MFMA(WH[kb], hL[kb], acc2[nt]);
            acc2[nt] = MFMA(WL[kb], hH[kb], acc2[nt]);
        }
    }

    // ---- epilogue 2: bias (+relu) -> bf16 row-major global ----
    size_t row = (size_t)r0 + m16;
#pragma unroll
    for (int nt = 0; nt < 8; ++nt) {
        int col = nt * 16 + quad * 4;
        ushort4 o;
#pragma unroll
        for (int rg = 0; rg < 4; ++rg) {
            float v = acc2[nt][rg] + b2[col + rg];
            if (relu) v = fmaxf(v, 0.f);
            ((u16*)&o)[rg] = f2bf(v);
        }
        *(ushort4*)(hout + row * 128 + col) = o;
    }
}

// ===========================================================================
// pool stage 1 (reads bf16 row-major node_emb): segment-boundary flush
// ===========================================================================
__global__ __launch_bounds__(256) void psum_kernel(const u16* __restrict__ h,
                                                   const int* __restrict__ batch,
                                                   float* __restrict__ sums) {
    __shared__ int sBatch[128];
    int blk = blockIdx.x, t = threadIdx.x;
    int n0 = blk * 128;
    int nEnd = min(n0 + 128, N_NODES);
    if (t < 128 && n0 + t < N_NODES) sBatch[t] = batch[n0 + t];
    __syncthreads();

    int j = t & 127;
    int half = t >> 7;
    int s = n0 + half * 64;
    int e = min(s + 64, nEnd);

    float acc = 0.f;
    int cur = -1;
    for (int n = s; n < e; ++n) {
        int g = sBatch[n - n0];
        if (g != cur) {
            if (cur >= 0) atomicAdd(&sums[cur * 128 + j], acc);
            cur = g;
            acc = 0.f;
        }
        acc += bf2f(h[(size_t)n * 128 + j]);
    }
    if (cur >= 0) atomicAdd(&sums[cur * 128 + j], acc);
}

// pool stage 2: counts by binary search, divide.
__global__ __launch_bounds__(128) void pdiv_kernel(const float* __restrict__ sums,
                                                   const int* __restrict__ batch,
                                                   float* __restrict__ out) {
    __shared__ int sB[2];
    int g = blockIdx.x;
    if (threadIdx.x < 2) {
        int target = g + threadIdx.x;
        int lo = 0, hi = N_NODES;
        while (lo < hi) {
            int m = (lo + hi) >> 1;
            if (batch[m] < target) lo = m + 1; else hi = m;
        }
        sB[threadIdx.x] = lo;
    }
    __syncthreads();
    float cnt = (float)(sB[1] - sB[0]);
    out[g * 128 + threadIdx.x] = sums[g * 128 + threadIdx.x] / fmaxf(cnt, 1.f);
}

// ===========================================================================
extern "C" void kernel_launch(void* const* d_in, const int* in_sizes, int n_in,
                              void* d_out, int out_size, void* d_ws, size_t ws_size,
                              hipStream_t stream) {
    const float* x     = (const float*)d_in[0];
    const int*   ei    = (const int*)d_in[1];
    const int*   batch = (const int*)d_in[2];
    const int*   eSrc  = ei;
    const int*   eDst  = ei + N_EDGES;

    const float* W1[3] = {(const float*)d_in[3], (const float*)d_in[7],  (const float*)d_in[11]};
    const float* b1[3] = {(const float*)d_in[4], (const float*)d_in[8],  (const float*)d_in[12]};
    const float* W2[3] = {(const float*)d_in[5], (const float*)d_in[9],  (const float*)d_in[13]};
    const float* b2[3] = {(const float*)d_in[6], (const float*)d_in[10], (const float*)d_in[14]};

    // workspace layout. Row-major ping-pong planes; planeB aliases the fp32
    // P2 region (pairs also aliases it -- temporally disjoint).
    float* P2 = (float*)d_ws;                          // fp32-sized region
    u16*   planeB = (u16*)P2;                          // ping-pong plane B
    u16*   planeA = (u16*)(P2 + (size_t)N_PAD * DIM);  // plane A (prep target)
    u16*   Ah = planeA + (size_t)N_PAD * DIM;          // dead region (layout keep)
    u16*   Wb = Ah + (size_t)N_PAD * DIM;              // 6 x 32768 u16
    int*   row_ptr = (int*)(Wb + 6 * 32768);           // N_NODES + 8
    u32*   cursorB = (u32*)(row_ptr + N_NODES + 8);    // 128
    int*   csr     = (int*)(cursorB + 128);            // N_EDGES
    float* sums    = (float*)(csr + N_EDGES);          // [128,128]
    u32*   pairs   = (u32*)P2;                         // aliases plane B (disjoint lifetime)

    // ---- CSR build ----
    hipMemsetAsync(cursorB, 0, 128 * sizeof(u32), stream);
    bucket1_kernel<<<B1_GRID, 256, 0, stream>>>(eSrc, eDst, cursorB, pairs);
    bucket2_kernel<<<NBKT, 1024, 0, stream>>>(cursorB, pairs, row_ptr, csr);

    // ---- merged prep: x->bf16 plane A, W planes, zero sums ----
    WPrepArgs wp;
    for (int l = 0; l < 3; ++l) {
        wp.w[2 * l]       = W1[l];
        wp.w[2 * l + 1]   = W2[l];
        wp.buf[2 * l]     = Wb + (size_t)(2 * l) * 32768;
        wp.buf[2 * l + 1] = Wb + (size_t)(2 * l + 1) * 32768;
    }
    prep_kernel<<<XPREP_BLKS + WPREP_BLKS + SUMS_BLKS, 256, 0, stream>>>(x, planeA, wp, sums);

    // ---- 3 fused barrier-free layers, ping-pong planes ----
    u16* hin  = planeA;
    u16* hout = planeB;
    for (int l = 0; l < 3; ++l) {
        gin_layer<<<GRID_FUSED, 256, 0, stream>>>(hin, row_ptr, csr,
                                                  Wb + (size_t)(2 * l) * 32768, b1[l],
                                                  Wb + (size_t)(2 * l + 1) * 32768, b2[l],
                                                  hout, (l < 2) ? 1 : 0);
        u16* tmp = hin; hin = hout; hout = tmp;
    }
    // after 3 swaps, final output is in `hin` (= planeB)
    psum_kernel<<<POOL_BLKS, 256, 0, stream>>>(hin, batch, sums);
    pdiv_kernel<<<N_GRAPHS, 128, 0, stream>>>(sums, batch, (float*)d_out);
}

// Round 13
// 485.042 us; speedup vs baseline: 1.3508x; 1.3508x over previous
//
#include <hip/hip_runtime.h>
#include <hip/hip_bf16.h>

#define N_NODES 100000
#define N_PAD   100032          // 1563 * 64
#define N_EDGES 1600000
#define DIM 128
#define N_GRAPHS 128
#define NBKT 98                 // ceil(100000/1024)
#define BSTRIDE 18432           // bucket capacity (mean 16384, +16 sigma)
#define TILES (N_PAD / 16)      // 6252 row-tiles of 16
#define GRID_FUSED 1563         // one 64-row group per block
#define POOL_BLKS ((N_NODES + 127) / 128)   // 782
#define B1_BATCH 4096
#define B1_GRID ((N_EDGES + B1_BATCH - 1) / B1_BATCH)   // 391

typedef unsigned short u16;
typedef unsigned int u32;
typedef __attribute__((ext_vector_type(8))) short bf16x8;
typedef __attribute__((ext_vector_type(8))) unsigned short u16x8;
typedef __attribute__((ext_vector_type(4))) float f32x4;

#define MFMA(A, B, C) __builtin_amdgcn_mfma_f32_16x16x32_bf16(A, B, C, 0, 0, 0)

__device__ __forceinline__ u16 f2bf(float x) {
    u32 u = __float_as_uint(x);
    u = (u + 0x7FFFu + ((u >> 16) & 1u)) >> 16;
    return (u16)u;
}
__device__ __forceinline__ float bf2f(u16 u) {
    return __uint_as_float(((u32)u) << 16);
}

// ===========================================================================
// bucket phase 1: append packed (dstLocal<<22 | src) to coarse buckets.
// ===========================================================================
__global__ __launch_bounds__(256) void bucket1_kernel(const int* __restrict__ src,
                                                      const int* __restrict__ dst,
                                                      u32* __restrict__ cursorB,
                                                      u32* __restrict__ pairs) {
    __shared__ int lh[NBKT];
    __shared__ u32 lbase[NBKT];
    int t = threadIdx.x;
    if (t < NBKT) lh[t] = 0;
    __syncthreads();
    int e0 = blockIdx.x * B1_BATCH;
    int d[16], s[16], rk[16];
#pragma unroll
    for (int k = 0; k < 16; ++k) {
        int e = e0 + t + k * 256;
        if (e < N_EDGES) {
            d[k] = dst[e];
            s[k] = src[e];
            rk[k] = atomicAdd(&lh[d[k] >> 10], 1);
        }
    }
    __syncthreads();
    if (t < NBKT) lbase[t] = atomicAdd(&cursorB[t], (u32)lh[t]) + (u32)(t * BSTRIDE);
    __syncthreads();
#pragma unroll
    for (int k = 0; k < 16; ++k) {
        int e = e0 + t + k * 256;
        if (e < N_EDGES) {
            u32 pos = lbase[d[k] >> 10] + (u32)rk[k];
            pairs[pos] = ((u32)(d[k] & 1023) << 22) | (u32)s[k];
        }
    }
}

// ===========================================================================
// bucket phase 2: per-bucket hist + scan -> row_ptr, then scatter into csr.
// ===========================================================================
__global__ __launch_bounds__(1024) void bucket2_kernel(const u32* __restrict__ cursorB,
                                                       const u32* __restrict__ pairs,
                                                       int* __restrict__ row_ptr,
                                                       int* __restrict__ csr) {
    __shared__ int lh[1024];
    __shared__ int rc[1024];
    __shared__ int bs[128];
    int b = blockIdx.x, t = threadIdx.x;

    if (t < 128) bs[t] = (t < NBKT) ? (int)cursorB[t] : 0;
    __syncthreads();
    for (int off = 1; off < 128; off <<= 1) {
        int v = (t < 128 && t >= off) ? bs[t - off] : 0;
        __syncthreads();
        if (t < 128) bs[t] += v;
        __syncthreads();
    }
    int cnt = (int)cursorB[b];
    int bbase = (b == 0) ? 0 : bs[b - 1];

    lh[t] = 0;
    __syncthreads();
    const u32* pb = pairs + (size_t)b * BSTRIDE;
    for (int i = t; i < cnt; i += 1024) atomicAdd(&lh[__builtin_nontemporal_load(pb + i) >> 22], 1);
    __syncthreads();

    int own = lh[t];
    for (int off = 1; off < 1024; off <<= 1) {
        int v = (t >= off) ? lh[t - off] : 0;
        __syncthreads();
        lh[t] += v;
        __syncthreads();
    }
    int excl = lh[t] - own;
    int node = b * 1024 + t;
    if (node < N_NODES) row_ptr[node] = bbase + excl;
    if (b == 0 && t == 0) row_ptr[N_NODES] = N_EDGES;
    rc[t] = bbase + excl;
    __syncthreads();

    for (int i = t; i < cnt; i += 1024) {
        u32 p = __builtin_nontemporal_load(pb + i);
        int pos = atomicAdd(&rc[p >> 22], 1);
        csr[pos] = (int)(p & 0x3FFFFFu);
    }
}

// ===========================================================================
// x -> bf16 hi plane (row-major), once per launch
// ===========================================================================
__global__ __launch_bounds__(256) void xprep_kernel(const float* __restrict__ x,
                                                    u16* __restrict__ hb) {
    int i = blockIdx.x * 256 + threadIdx.x;
    if (i < N_NODES * 32) {
        float4 v = ((const float4*)x)[i];
        ushort4 o;
        o.x = f2bf(v.x); o.y = f2bf(v.y); o.z = f2bf(v.z); o.w = f2bf(v.w);
        ((ushort4*)hb)[i] = o;
    }
}

// ===========================================================================
// W prep: fp32 W[k][n] -> WT planes: hi at [n*128+k], lo at [n*128+k + 16384]
// ===========================================================================
struct WPrepArgs {
    const float* w[6];
    u16* buf[6];
};
__global__ __launch_bounds__(256) void wprep_kernel(WPrepArgs p) {
    int m = blockIdx.y;
    int idx = blockIdx.x * 256 + threadIdx.x;   // n*128 + k
    int n = idx >> 7, k = idx & 127;
    float v = p.w[m][k * 128 + n];
    u16 hi = f2bf(v);
    p.buf[m][idx] = hi;
    p.buf[m][idx + 16384] = f2bf(v - bf2f(hi));
}

// ===========================================================================
// FUSED gin layer -- the R18 winner (489.0us total), exact revert.
// Overlap ledger (all falsified): R19 occupancy (BW fell), R21 wave
// specialization (gather waves halved), R22/R23 XCD slicing (over-fetch /
// latency-bound), R24 barrier-free per-wave (W-reload bloat). The cohort-
// synchronized 64-row fusion keeps all 16 waves/CU gathering at the
// measured ~3.4 TB/s random-gather ceiling, then pays the ~37us MLP phase
// serially -- empirically the best operating point on this hardware.
// ===========================================================================
#define HS 136
__global__ __launch_bounds__(256, 2) void gin_layer(const u16* __restrict__ hin,
                                                    const int* __restrict__ rp,
                                                    const int* __restrict__ csr,
                                                    const u16* __restrict__ W1,
                                                    const float* __restrict__ b1,
                                                    const u16* __restrict__ W2,
                                                    const float* __restrict__ b2,
                                                    u16* __restrict__ hout, int relu) {
    __shared__ u16 Hh[64 * HS];
    __shared__ u16 Hl[64 * HS];
    int tid = threadIdx.x;
    int lane = tid & 63, wave = tid >> 6;
    int m16 = lane & 15, quad = lane >> 4;
    int colBase = wave * 32;
    int t0 = blockIdx.x * 4;            // first 16-row tile
    int r0 = t0 * 16;                   // first node row of this block

    // ================= gather phase: 64 rows -> Hh (bf16) =================
    {
        int qw = tid >> 4;              // quarter-wave 0..15, one node at a time
        int f  = tid & 15;              // feature lane: cols f*8 .. f*8+7
        int nb = r0 + qw * 4;
        const u16x8* h8 = (const u16x8*)hin;
#pragma unroll
        for (int j = 0; j < 4; ++j) {
            int n = nb + j;
            int nl = qw * 4 + j;
            float a[8];
            if (n < N_NODES) {
                u16x8 sv = h8[(size_t)n * 16 + f];
#pragma unroll
                for (int r = 0; r < 8; ++r) a[r] = bf2f(sv[r]);
                int s = rp[n], e = rp[n + 1];
                int i = s;
                for (; i + 8 <= e; i += 8) {
                    u16x8 v0 = h8[(size_t)csr[i + 0] * 16 + f];
                    u16x8 v1 = h8[(size_t)csr[i + 1] * 16 + f];
                    u16x8 v2 = h8[(size_t)csr[i + 2] * 16 + f];
                    u16x8 v3 = h8[(size_t)csr[i + 3] * 16 + f];
                    u16x8 v4 = h8[(size_t)csr[i + 4] * 16 + f];
                    u16x8 v5 = h8[(size_t)csr[i + 5] * 16 + f];
                    u16x8 v6 = h8[(size_t)csr[i + 6] * 16 + f];
                    u16x8 v7 = h8[(size_t)csr[i + 7] * 16 + f];
#pragma unroll
                    for (int r = 0; r < 8; ++r)
                        a[r] += ((bf2f(v0[r]) + bf2f(v1[r])) + (bf2f(v2[r]) + bf2f(v3[r]))) +
                                ((bf2f(v4[r]) + bf2f(v5[r])) + (bf2f(v6[r]) + bf2f(v7[r])));
                }
                for (; i < e; ++i) {
                    u16x8 v = h8[(size_t)csr[i] * 16 + f];
#pragma unroll
                    for (int r = 0; r < 8; ++r) a[r] += bf2f(v[r]);
                }
            } else {
#pragma unroll
                for (int r = 0; r < 8; ++r) a[r] = 0.f;
            }
            u16x8 o;
#pragma unroll
            for (int r = 0; r < 8; ++r) o[r] = f2bf(a[r]);
            *(u16x8*)&Hh[nl * HS + f * 8] = o;
        }
    }
    __syncthreads();   // all 64 aggregated rows visible

    // ---- load A frags from LDS ----
    bf16x8 aH[4][4];
#pragma unroll
    for (int p = 0; p < 4; ++p)
#pragma unroll
        for (int kb = 0; kb < 4; ++kb)
            aH[p][kb] = *(const bf16x8*)&Hh[(p * 16 + m16) * HS + kb * 32 + quad * 8];
    __syncthreads();   // frag reads complete before epilogue1 overwrites Hh

    float b1v[2][4], b2v[2][4];
#pragma unroll
    for (int nt = 0; nt < 2; ++nt)
#pragma unroll
        for (int rg = 0; rg < 4; ++rg) {
            int col = colBase + nt * 16 + quad * 4 + rg;
            b1v[nt][rg] = b1[col];
            b2v[nt][rg] = b2[col];
        }

    f32x4 z = {0.f, 0.f, 0.f, 0.f};

    // ---- load W1 frags (pass-1 lifetime only) ----
    bf16x8 W1H[2][4], W1L[2][4];
#pragma unroll
    for (int nt = 0; nt < 2; ++nt) {
        int n = colBase + nt * 16 + m16;
#pragma unroll
        for (int kb = 0; kb < 4; ++kb) {
            int off = n * 128 + kb * 32 + quad * 8;
            W1H[nt][kb] = *(const bf16x8*)(W1 + off);
            W1L[nt][kb] = *(const bf16x8*)(W1 + off + 16384);
        }
    }

    f32x4 acc[4][2];
#pragma unroll
    for (int p = 0; p < 4; ++p) { acc[p][0] = z; acc[p][1] = z; }

    // ---- pass 1: (W1H + W1L) x aH ----
#pragma unroll
    for (int kb = 0; kb < 4; ++kb) {
#pragma unroll
        for (int p = 0; p < 4; ++p) {
            acc[p][0] = MFMA(W1H[0][kb], aH[p][kb], acc[p][0]);
            acc[p][1] = MFMA(W1H[1][kb], aH[p][kb], acc[p][1]);
            acc[p][0] = MFMA(W1L[0][kb], aH[p][kb], acc[p][0]);
            acc[p][1] = MFMA(W1L[1][kb], aH[p][kb], acc[p][1]);
        }
    }

    // ---- epilogue 1: bias+relu+split -> LDS ----
#pragma unroll
    for (int p = 0; p < 4; ++p) {
#pragma unroll
        for (int nt = 0; nt < 2; ++nt) {
            ushort4 hv, lv;
#pragma unroll
            for (int rg = 0; rg < 4; ++rg) {
                float v = fmaxf(acc[p][nt][rg] + b1v[nt][rg], 0.f);
                u16 hi = f2bf(v);
                ((u16*)&hv)[rg] = hi;
                ((u16*)&lv)[rg] = f2bf(v - bf2f(hi));
            }
            int off = (p * 16 + m16) * HS + colBase + nt * 16 + quad * 4;
            *(ushort4*)&Hh[off] = hv;
            *(ushort4*)&Hl[off] = lv;
        }
    }
    __syncthreads();   // H visible to all waves

    // ---- load W2 frags (pass-2 lifetime only) ----
    bf16x8 W2H[2][4], W2L[2][4];
#pragma unroll
    for (int nt = 0; nt < 2; ++nt) {
        int n = colBase + nt * 16 + m16;
#pragma unroll
        for (int kb = 0; kb < 4; ++kb) {
            int off = n * 128 + kb * 32 + quad * 8;
            W2H[nt][kb] = *(const bf16x8*)(W2 + off);
            W2L[nt][kb] = *(const bf16x8*)(W2 + off + 16384);
        }
    }

    // ---- pass 2: W2 x H (H hi/lo) ----
    f32x4 acc2[4][2];
#pragma unroll
    for (int p = 0; p < 4; ++p) { acc2[p][0] = z; acc2[p][1] = z; }
#pragma unroll
    for (int kb = 0; kb < 4; ++kb) {
#pragma unroll
        for (int p = 0; p < 4; ++p) {
            int off = (p * 16 + m16) * HS + kb * 32 + quad * 8;
            bf16x8 hH = *(const bf16x8*)(&Hh[off]);
            bf16x8 hL = *(const bf16x8*)(&Hl[off]);
            acc2[p][0] = MFMA(W2H[0][kb], hH, acc2[p][0]);
            acc2[p][1] = MFMA(W2H[1][kb], hH, acc2[p][1]);
            acc2[p][0] = MFMA(W2H[0][kb], hL, acc2[p][0]);
            acc2[p][1] = MFMA(W2H[1][kb], hL, acc2[p][1]);
            acc2[p][0] = MFMA(W2L[0][kb], hH, acc2[p][0]);
            acc2[p][1] = MFMA(W2L[1][kb], hH, acc2[p][1]);
        }
    }

    // ---- epilogue 2: bias (+relu) -> bf16 global ----
#pragma unroll
    for (int p = 0; p < 4; ++p) {
        size_t row = (size_t)(t0 + p) * 16 + m16;
#pragma unroll
        for (int nt = 0; nt < 2; ++nt) {
            int col = colBase + nt * 16 + quad * 4;
            ushort4 o;
#pragma unroll
            for (int rg = 0; rg < 4; ++rg) {
                float v = acc2[p][nt][rg] + b2v[nt][rg];
                if (relu) v = fmaxf(v, 0.f);
                ((u16*)&o)[rg] = f2bf(v);
            }
            *(ushort4*)(hout + row * 128 + col) = o;
        }
    }
}

// ===========================================================================
// pool stage 1 (reads bf16 node_emb): segment-boundary flush into sums
// ===========================================================================
__global__ __launch_bounds__(256) void psum_kernel(const u16* __restrict__ h,
                                                   const int* __restrict__ batch,
                                                   float* __restrict__ sums) {
    __shared__ int sBatch[128];
    int blk = blockIdx.x, t = threadIdx.x;
    int n0 = blk * 128;
    int nEnd = min(n0 + 128, N_NODES);
    if (t < 128 && n0 + t < N_NODES) sBatch[t] = batch[n0 + t];
    __syncthreads();

    int j = t & 127;
    int half = t >> 7;
    int s = n0 + half * 64;
    int e = min(s + 64, nEnd);

    float acc = 0.f;
    int cur = -1;
    for (int n = s; n < e; ++n) {
        int g = sBatch[n - n0];
        if (g != cur) {
            if (cur >= 0) atomicAdd(&sums[cur * 128 + j], acc);
            cur = g;
            acc = 0.f;
        }
        acc += bf2f(h[(size_t)n * 128 + j]);
    }
    if (cur >= 0) atomicAdd(&sums[cur * 128 + j], acc);
}

// pool stage 2: counts by binary search, divide.
__global__ __launch_bounds__(128) void pdiv_kernel(const float* __restrict__ sums,
                                                   const int* __restrict__ batch,
                                                   float* __restrict__ out) {
    __shared__ int sB[2];
    int g = blockIdx.x;
    if (threadIdx.x < 2) {
        int target = g + threadIdx.x;
        int lo = 0, hi = N_NODES;
        while (lo < hi) {
            int m = (lo + hi) >> 1;
            if (batch[m] < target) lo = m + 1; else hi = m;
        }
        sB[threadIdx.x] = lo;
    }
    __syncthreads();
    float cnt = (float)(sB[1] - sB[0]);
    out[g * 128 + threadIdx.x] = sums[g * 128 + threadIdx.x] / fmaxf(cnt, 1.f);
}

// ===========================================================================
extern "C" void kernel_launch(void* const* d_in, const int* in_sizes, int n_in,
                              void* d_out, int out_size, void* d_ws, size_t ws_size,
                              hipStream_t stream) {
    const float* x     = (const float*)d_in[0];
    const int*   ei    = (const int*)d_in[1];
    const int*   batch = (const int*)d_in[2];
    const int*   eSrc  = ei;
    const int*   eDst  = ei + N_EDGES;

    const float* W1[3] = {(const float*)d_in[3], (const float*)d_in[7],  (const float*)d_in[11]};
    const float* b1[3] = {(const float*)d_in[4], (const float*)d_in[8],  (const float*)d_in[12]};
    const float* W2[3] = {(const float*)d_in[5], (const float*)d_in[9],  (const float*)d_in[13]};
    const float* b2[3] = {(const float*)d_in[6], (const float*)d_in[10], (const float*)d_in[14]};

    // workspace layout. Ping-pong h-planes: plane0 = hb slot, plane1 carved
    // from the old P2 fp32 region (pairs also aliases it -- temporally
    // disjoint: CSR build completes before layer 0 runs).
    float* P2 = (float*)d_ws;                          // [N_PAD,128] fp32 region
    u16*   planeB = (u16*)P2;                          // layer ping-pong plane B
    u16*   planeA = (u16*)(P2 + (size_t)N_PAD * DIM);  // plane A (xprep target)
    u16*   Ah = planeA + (size_t)N_PAD * DIM;          // (unused now, kept for layout)
    u16*   Wb = Ah + (size_t)N_PAD * DIM;              // 6 x 32768 u16
    int*   row_ptr = (int*)(Wb + 6 * 32768);           // N_NODES + 8
    u32*   cursorB = (u32*)(row_ptr + N_NODES + 8);    // 128
    int*   csr     = (int*)(cursorB + 128);            // N_EDGES
    float* sums    = (float*)(csr + N_EDGES);          // [128,128]
    u32*   pairs   = (u32*)P2;                         // aliases plane B (disjoint lifetime)

    // ---- CSR build ----
    hipMemsetAsync(cursorB, 0, 128 * sizeof(u32), stream);
    bucket1_kernel<<<B1_GRID, 256, 0, stream>>>(eSrc, eDst, cursorB, pairs);
    bucket2_kernel<<<NBKT, 1024, 0, stream>>>(cursorB, pairs, row_ptr, csr);

    // ---- x -> bf16 plane A, W prep, zero pool sums ----
    xprep_kernel<<<(N_NODES * 32 + 255) / 256, 256, 0, stream>>>(x, planeA);
    WPrepArgs wp;
    for (int l = 0; l < 3; ++l) {
        wp.w[2 * l]       = W1[l];
        wp.w[2 * l + 1]   = W2[l];
        wp.buf[2 * l]     = Wb + (size_t)(2 * l) * 32768;
        wp.buf[2 * l + 1] = Wb + (size_t)(2 * l + 1) * 32768;
    }
    wprep_kernel<<<dim3(64, 6), 256, 0, stream>>>(wp);
    hipMemsetAsync(sums, 0, N_GRAPHS * DIM * sizeof(float), stream);

    // ---- 3 fused layers, ping-pong planes ----
    u16* hin  = planeA;
    u16* hout = planeB;
    for (int l = 0; l < 3; ++l) {
        gin_layer<<<GRID_FUSED, 256, 0, stream>>>(hin, row_ptr, csr,
                                                  Wb + (size_t)(2 * l) * 32768, b1[l],
                                                  Wb + (size_t)(2 * l + 1) * 32768, b2[l],
                                                  hout, (l < 2) ? 1 : 0);
        u16* tmp = hin; hin = hout; hout = tmp;
    }
    // after 3 swaps, final output is in `hin` (= planeB)
    psum_kernel<<<POOL_BLKS, 256, 0, stream>>>(hin, batch, sums);
    pdiv_kernel<<<N_GRAPHS, 128, 0, stream>>>(sums, batch, (float*)d_out);
}

// Round 14
// 481.249 us; speedup vs baseline: 1.3614x; 1.0079x over previous
//
#include <hip/hip_runtime.h>
#include <hip/hip_bf16.h>

#define N_NODES 100000
#define N_PAD   100032          // 1563 * 64
#define N_EDGES 1600000
#define DIM 128
#define N_GRAPHS 128
#define NBKT 98                 // ceil(100000/1024)
#define BSTRIDE 18432           // bucket capacity (mean 16384, +16 sigma)
#define TILES (N_PAD / 16)      // 6252 row-tiles of 16
#define GRID_FUSED 1563         // one 64-row group per block
#define POOL_BLKS ((N_NODES + 127) / 128)   // 782
#define B1_BATCH 4096
#define B1_GRID ((N_EDGES + B1_BATCH - 1) / B1_BATCH)   // 391
#define XPREP_BLKS 12500        // N_NODES*32 / 256
#define WPREP_BLKS_1K 96        // 6*16384 / 1024
#define SUMS_BLKS_1K 16         // 16384 / 1024

typedef unsigned short u16;
typedef unsigned int u32;
typedef __attribute__((ext_vector_type(8))) short bf16x8;
typedef __attribute__((ext_vector_type(8))) unsigned short u16x8;
typedef __attribute__((ext_vector_type(4))) float f32x4;

#define MFMA(A, B, C) __builtin_amdgcn_mfma_f32_16x16x32_bf16(A, B, C, 0, 0, 0)

__device__ __forceinline__ u16 f2bf(float x) {
    u32 u = __float_as_uint(x);
    u = (u + 0x7FFFu + ((u >> 16) & 1u)) >> 16;
    return (u16)u;
}
__device__ __forceinline__ float bf2f(u16 u) {
    return __uint_as_float(((u32)u) << 16);
}

struct WPrepArgs {
    const float* w[6];
    u16* buf[6];
};

// ===========================================================================
// build_prep_a (R26): bucket1 (blocks 0..390) co-scheduled with xprep
// (blocks 391..12890). The two are data-independent; xprep's BW burst hides
// bucket1's atomic scatter. Bodies byte-identical to the proven kernels.
// ===========================================================================
__global__ __launch_bounds__(256) void build_prep_a(const int* __restrict__ src,
                                                    const int* __restrict__ dst,
                                                    u32* __restrict__ cursorB,
                                                    u32* __restrict__ pairs,
                                                    const float* __restrict__ x,
                                                    u16* __restrict__ hb) {
    __shared__ int lh[NBKT];
    __shared__ u32 lbase[NBKT];
    int t = threadIdx.x;
    if (blockIdx.x < B1_GRID) {
        // ---- bucket1: append packed (dstLocal<<22 | src) to coarse buckets
        if (t < NBKT) lh[t] = 0;
        __syncthreads();
        int e0 = blockIdx.x * B1_BATCH;
        int d[16], s[16], rk[16];
#pragma unroll
        for (int k = 0; k < 16; ++k) {
            int e = e0 + t + k * 256;
            if (e < N_EDGES) {
                d[k] = dst[e];
                s[k] = src[e];
                rk[k] = atomicAdd(&lh[d[k] >> 10], 1);
            }
        }
        __syncthreads();
        if (t < NBKT) lbase[t] = atomicAdd(&cursorB[t], (u32)lh[t]) + (u32)(t * BSTRIDE);
        __syncthreads();
#pragma unroll
        for (int k = 0; k < 16; ++k) {
            int e = e0 + t + k * 256;
            if (e < N_EDGES) {
                u32 pos = lbase[d[k] >> 10] + (u32)rk[k];
                pairs[pos] = ((u32)(d[k] & 1023) << 22) | (u32)s[k];
            }
        }
    } else {
        // ---- xprep: x -> bf16 hi plane (row-major)
        int i = (blockIdx.x - B1_GRID) * 256 + t;
        if (i < N_NODES * 32) {
            float4 v = ((const float4*)x)[i];
            ushort4 o;
            o.x = f2bf(v.x); o.y = f2bf(v.y); o.z = f2bf(v.z); o.w = f2bf(v.w);
            ((ushort4*)hb)[i] = o;
        }
    }
}

// ===========================================================================
// build_prep_b (R26): bucket2 (blocks 0..97) co-scheduled with wprep
// (96 blocks) and sums-zero (16 blocks). bucket2 is latency-bound on 98
// blocks; the prep blocks backfill the idle CUs and two launch gaps + one
// memset disappear. Bodies byte-identical to the proven kernels.
// ===========================================================================
__global__ __launch_bounds__(1024) void build_prep_b(const u32* __restrict__ cursorB,
                                                     const u32* __restrict__ pairs,
                                                     int* __restrict__ row_ptr,
                                                     int* __restrict__ csr,
                                                     WPrepArgs p,
                                                     float* __restrict__ sums) {
    __shared__ int lh[1024];
    __shared__ int rc[1024];
    __shared__ int bs[128];
    int t = threadIdx.x;
    if (blockIdx.x < NBKT) {
        // ---- bucket2: per-bucket hist + scan -> row_ptr, scatter into csr
        int b = blockIdx.x;
        if (t < 128) bs[t] = (t < NBKT) ? (int)cursorB[t] : 0;
        __syncthreads();
        for (int off = 1; off < 128; off <<= 1) {
            int v = (t < 128 && t >= off) ? bs[t - off] : 0;
            __syncthreads();
            if (t < 128) bs[t] += v;
            __syncthreads();
        }
        int cnt = (int)cursorB[b];
        int bbase = (b == 0) ? 0 : bs[b - 1];

        lh[t] = 0;
        __syncthreads();
        const u32* pb = pairs + (size_t)b * BSTRIDE;
        for (int i = t; i < cnt; i += 1024) atomicAdd(&lh[__builtin_nontemporal_load(pb + i) >> 22], 1);
        __syncthreads();

        int own = lh[t];
        for (int off = 1; off < 1024; off <<= 1) {
            int v = (t >= off) ? lh[t - off] : 0;
            __syncthreads();
            lh[t] += v;
            __syncthreads();
        }
        int excl = lh[t] - own;
        int node = b * 1024 + t;
        if (node < N_NODES) row_ptr[node] = bbase + excl;
        if (b == 0 && t == 0) row_ptr[N_NODES] = N_EDGES;
        rc[t] = bbase + excl;
        __syncthreads();

        for (int i = t; i < cnt; i += 1024) {
            u32 pr = __builtin_nontemporal_load(pb + i);
            int pos = atomicAdd(&rc[pr >> 22], 1);
            csr[pos] = (int)(pr & 0x3FFFFFu);
        }
    } else if (blockIdx.x < NBKT + WPREP_BLKS_1K) {
        // ---- wprep: fp32 W[k][n] -> hi at [n*128+k], lo at +16384
        int i = (blockIdx.x - NBKT) * 1024 + t;     // 0..98303
        int m = i >> 14;                            // matrix 0..5
        int idx = i & 16383;                        // n*128 + k
        int n = idx >> 7, k = idx & 127;
        float v = p.w[m][k * 128 + n];
        u16 hi = f2bf(v);
        p.buf[m][idx] = hi;
        p.buf[m][idx + 16384] = f2bf(v - bf2f(hi));
    } else {
        // ---- sums zero
        int i = (blockIdx.x - NBKT - WPREP_BLKS_1K) * 1024 + t;
        if (i < N_GRAPHS * DIM) sums[i] = 0.f;
    }
}

// ===========================================================================
// FUSED gin layer -- the R18 winner (485.0us total), unchanged.
// Overlap ledger (all falsified): R19 occupancy (BW fell), R21 wave
// specialization (gather waves halved), R22/R23 XCD slicing (over-fetch /
// latency-bound), R24 barrier-free per-wave (W-reload bloat). The cohort-
// synchronized 64-row fusion keeps all 16 waves/CU gathering at the
// measured ~3.4 TB/s random-gather ceiling, then pays the ~37us MLP phase
// serially -- empirically the best operating point on this hardware.
// ===========================================================================
#define HS 136
__global__ __launch_bounds__(256, 2) void gin_layer(const u16* __restrict__ hin,
                                                    const int* __restrict__ rp,
                                                    const int* __restrict__ csr,
                                                    const u16* __restrict__ W1,
                                                    const float* __restrict__ b1,
                                                    const u16* __restrict__ W2,
                                                    const float* __restrict__ b2,
                                                    u16* __restrict__ hout, int relu) {
    __shared__ u16 Hh[64 * HS];
    __shared__ u16 Hl[64 * HS];
    int tid = threadIdx.x;
    int lane = tid & 63, wave = tid >> 6;
    int m16 = lane & 15, quad = lane >> 4;
    int colBase = wave * 32;
    int t0 = blockIdx.x * 4;            // first 16-row tile
    int r0 = t0 * 16;                   // first node row of this block

    // ================= gather phase: 64 rows -> Hh (bf16) =================
    {
        int qw = tid >> 4;              // quarter-wave 0..15, one node at a time
        int f  = tid & 15;              // feature lane: cols f*8 .. f*8+7
        int nb = r0 + qw * 4;
        const u16x8* h8 = (const u16x8*)hin;
#pragma unroll
        for (int j = 0; j < 4; ++j) {
            int n = nb + j;
            int nl = qw * 4 + j;
            float a[8];
            if (n < N_NODES) {
                u16x8 sv = h8[(size_t)n * 16 + f];
#pragma unroll
                for (int r = 0; r < 8; ++r) a[r] = bf2f(sv[r]);
                int s = rp[n], e = rp[n + 1];
                int i = s;
                for (; i + 8 <= e; i += 8) {
                    u16x8 v0 = h8[(size_t)csr[i + 0] * 16 + f];
                    u16x8 v1 = h8[(size_t)csr[i + 1] * 16 + f];
                    u16x8 v2 = h8[(size_t)csr[i + 2] * 16 + f];
                    u16x8 v3 = h8[(size_t)csr[i + 3] * 16 + f];
                    u16x8 v4 = h8[(size_t)csr[i + 4] * 16 + f];
                    u16x8 v5 = h8[(size_t)csr[i + 5] * 16 + f];
                    u16x8 v6 = h8[(size_t)csr[i + 6] * 16 + f];
                    u16x8 v7 = h8[(size_t)csr[i + 7] * 16 + f];
#pragma unroll
                    for (int r = 0; r < 8; ++r)
                        a[r] += ((bf2f(v0[r]) + bf2f(v1[r])) + (bf2f(v2[r]) + bf2f(v3[r]))) +
                                ((bf2f(v4[r]) + bf2f(v5[r])) + (bf2f(v6[r]) + bf2f(v7[r])));
                }
                for (; i < e; ++i) {
                    u16x8 v = h8[(size_t)csr[i] * 16 + f];
#pragma unroll
                    for (int r = 0; r < 8; ++r) a[r] += bf2f(v[r]);
                }
            } else {
#pragma unroll
                for (int r = 0; r < 8; ++r) a[r] = 0.f;
            }
            u16x8 o;
#pragma unroll
            for (int r = 0; r < 8; ++r) o[r] = f2bf(a[r]);
            *(u16x8*)&Hh[nl * HS + f * 8] = o;
        }
    }
    __syncthreads();   // all 64 aggregated rows visible

    // ---- load A frags from LDS ----
    bf16x8 aH[4][4];
#pragma unroll
    for (int p = 0; p < 4; ++p)
#pragma unroll
        for (int kb = 0; kb < 4; ++kb)
            aH[p][kb] = *(const bf16x8*)&Hh[(p * 16 + m16) * HS + kb * 32 + quad * 8];
    __syncthreads();   // frag reads complete before epilogue1 overwrites Hh

    float b1v[2][4], b2v[2][4];
#pragma unroll
    for (int nt = 0; nt < 2; ++nt)
#pragma unroll
        for (int rg = 0; rg < 4; ++rg) {
            int col = colBase + nt * 16 + quad * 4 + rg;
            b1v[nt][rg] = b1[col];
            b2v[nt][rg] = b2[col];
        }

    f32x4 z = {0.f, 0.f, 0.f, 0.f};

    // ---- load W1 frags (pass-1 lifetime only) ----
    bf16x8 W1H[2][4], W1L[2][4];
#pragma unroll
    for (int nt = 0; nt < 2; ++nt) {
        int n = colBase + nt * 16 + m16;
#pragma unroll
        for (int kb = 0; kb < 4; ++kb) {
            int off = n * 128 + kb * 32 + quad * 8;
            W1H[nt][kb] = *(const bf16x8*)(W1 + off);
            W1L[nt][kb] = *(const bf16x8*)(W1 + off + 16384);
        }
    }

    f32x4 acc[4][2];
#pragma unroll
    for (int p = 0; p < 4; ++p) { acc[p][0] = z; acc[p][1] = z; }

    // ---- pass 1: (W1H + W1L) x aH ----
#pragma unroll
    for (int kb = 0; kb < 4; ++kb) {
#pragma unroll
        for (int p = 0; p < 4; ++p) {
            acc[p][0] = MFMA(W1H[0][kb], aH[p][kb], acc[p][0]);
            acc[p][1] = MFMA(W1H[1][kb], aH[p][kb], acc[p][1]);
            acc[p][0] = MFMA(W1L[0][kb], aH[p][kb], acc[p][0]);
            acc[p][1] = MFMA(W1L[1][kb], aH[p][kb], acc[p][1]);
        }
    }

    // ---- epilogue 1: bias+relu+split -> LDS ----
#pragma unroll
    for (int p = 0; p < 4; ++p) {
#pragma unroll
        for (int nt = 0; nt < 2; ++nt) {
            ushort4 hv, lv;
#pragma unroll
            for (int rg = 0; rg < 4; ++rg) {
                float v = fmaxf(acc[p][nt][rg] + b1v[nt][rg], 0.f);
                u16 hi = f2bf(v);
                ((u16*)&hv)[rg] = hi;
                ((u16*)&lv)[rg] = f2bf(v - bf2f(hi));
            }
            int off = (p * 16 + m16) * HS + colBase + nt * 16 + quad * 4;
            *(ushort4*)&Hh[off] = hv;
            *(ushort4*)&Hl[off] = lv;
        }
    }
    __syncthreads();   // H visible to all waves

    // ---- load W2 frags (pass-2 lifetime only) ----
    bf16x8 W2H[2][4], W2L[2][4];
#pragma unroll
    for (int nt = 0; nt < 2; ++nt) {
        int n = colBase + nt * 16 + m16;
#pragma unroll
        for (int kb = 0; kb < 4; ++kb) {
            int off = n * 128 + kb * 32 + quad * 8;
            W2H[nt][kb] = *(const bf16x8*)(W2 + off);
            W2L[nt][kb] = *(const bf16x8*)(W2 + off + 16384);
        }
    }

    // ---- pass 2: W2 x H (H hi/lo) ----
    f32x4 acc2[4][2];
#pragma unroll
    for (int p = 0; p < 4; ++p) { acc2[p][0] = z; acc2[p][1] = z; }
#pragma unroll
    for (int kb = 0; kb < 4; ++kb) {
#pragma unroll
        for (int p = 0; p < 4; ++p) {
            int off = (p * 16 + m16) * HS + kb * 32 + quad * 8;
            bf16x8 hH = *(const bf16x8*)(&Hh[off]);
            bf16x8 hL = *(const bf16x8*)(&Hl[off]);
            acc2[p][0] = MFMA(W2H[0][kb], hH, acc2[p][0]);
            acc2[p][1] = MFMA(W2H[1][kb], hH, acc2[p][1]);
            acc2[p][0] = MFMA(W2H[0][kb], hL, acc2[p][0]);
            acc2[p][1] = MFMA(W2H[1][kb], hL, acc2[p][1]);
            acc2[p][0] = MFMA(W2L[0][kb], hH, acc2[p][0]);
            acc2[p][1] = MFMA(W2L[1][kb], hH, acc2[p][1]);
        }
    }

    // ---- epilogue 2: bias (+relu) -> bf16 global ----
#pragma unroll
    for (int p = 0; p < 4; ++p) {
        size_t row = (size_t)(t0 + p) * 16 + m16;
#pragma unroll
        for (int nt = 0; nt < 2; ++nt) {
            int col = colBase + nt * 16 + quad * 4;
            ushort4 o;
#pragma unroll
            for (int rg = 0; rg < 4; ++rg) {
                float v = acc2[p][nt][rg] + b2v[nt][rg];
                if (relu) v = fmaxf(v, 0.f);
                ((u16*)&o)[rg] = f2bf(v);
            }
            *(ushort4*)(hout + row * 128 + col) = o;
        }
    }
}

// ===========================================================================
// pool stage 1 (reads bf16 node_emb): segment-boundary flush into sums
// ===========================================================================
__global__ __launch_bounds__(256) void psum_kernel(const u16* __restrict__ h,
                                                   const int* __restrict__ batch,
                                                   float* __restrict__ sums) {
    __shared__ int sBatch[128];
    int blk = blockIdx.x, t = threadIdx.x;
    int n0 = blk * 128;
    int nEnd = min(n0 + 128, N_NODES);
    if (t < 128 && n0 + t < N_NODES) sBatch[t] = batch[n0 + t];
    __syncthreads();

    int j = t & 127;
    int half = t >> 7;
    int s = n0 + half * 64;
    int e = min(s + 64, nEnd);

    float acc = 0.f;
    int cur = -1;
    for (int n = s; n < e; ++n) {
        int g = sBatch[n - n0];
        if (g != cur) {
            if (cur >= 0) atomicAdd(&sums[cur * 128 + j], acc);
            cur = g;
            acc = 0.f;
        }
        acc += bf2f(h[(size_t)n * 128 + j]);
    }
    if (cur >= 0) atomicAdd(&sums[cur * 128 + j], acc);
}

// pool stage 2: counts by binary search, divide.
__global__ __launch_bounds__(128) void pdiv_kernel(const float* __restrict__ sums,
                                                   const int* __restrict__ batch,
                                                   float* __restrict__ out) {
    __shared__ int sB[2];
    int g = blockIdx.x;
    if (threadIdx.x < 2) {
        int target = g + threadIdx.x;
        int lo = 0, hi = N_NODES;
        while (lo < hi) {
            int m = (lo + hi) >> 1;
            if (batch[m] < target) lo = m + 1; else hi = m;
        }
        sB[threadIdx.x] = lo;
    }
    __syncthreads();
    float cnt = (float)(sB[1] - sB[0]);
    out[g * 128 + threadIdx.x] = sums[g * 128 + threadIdx.x] / fmaxf(cnt, 1.f);
}

// ===========================================================================
extern "C" void kernel_launch(void* const* d_in, const int* in_sizes, int n_in,
                              void* d_out, int out_size, void* d_ws, size_t ws_size,
                              hipStream_t stream) {
    const float* x     = (const float*)d_in[0];
    const int*   ei    = (const int*)d_in[1];
    const int*   batch = (const int*)d_in[2];
    const int*   eSrc  = ei;
    const int*   eDst  = ei + N_EDGES;

    const float* W1[3] = {(const float*)d_in[3], (const float*)d_in[7],  (const float*)d_in[11]};
    const float* b1[3] = {(const float*)d_in[4], (const float*)d_in[8],  (const float*)d_in[12]};
    const float* W2[3] = {(const float*)d_in[5], (const float*)d_in[9],  (const float*)d_in[13]};
    const float* b2[3] = {(const float*)d_in[6], (const float*)d_in[10], (const float*)d_in[14]};

    // workspace layout. Ping-pong h-planes: plane B aliases the old P2 fp32
    // region (pairs also aliases it -- temporally disjoint: CSR build
    // completes before layer 0 runs).
    float* P2 = (float*)d_ws;                          // [N_PAD,128] fp32 region
    u16*   planeB = (u16*)P2;                          // layer ping-pong plane B
    u16*   planeA = (u16*)(P2 + (size_t)N_PAD * DIM);  // plane A (xprep target)
    u16*   Ah = planeA + (size_t)N_PAD * DIM;          // (unused, layout keep)
    u16*   Wb = Ah + (size_t)N_PAD * DIM;              // 6 x 32768 u16
    int*   row_ptr = (int*)(Wb + 6 * 32768);           // N_NODES + 8
    u32*   cursorB = (u32*)(row_ptr + N_NODES + 8);    // 128
    int*   csr     = (int*)(cursorB + 128);            // N_EDGES
    float* sums    = (float*)(csr + N_EDGES);          // [128,128]
    u32*   pairs   = (u32*)P2;                         // aliases plane B (disjoint lifetime)

    WPrepArgs wp;
    for (int l = 0; l < 3; ++l) {
        wp.w[2 * l]       = W1[l];
        wp.w[2 * l + 1]   = W2[l];
        wp.buf[2 * l]     = Wb + (size_t)(2 * l) * 32768;
        wp.buf[2 * l + 1] = Wb + (size_t)(2 * l + 1) * 32768;
    }

    // ---- stage A: bucket1 || xprep (independent) ----
    hipMemsetAsync(cursorB, 0, 128 * sizeof(u32), stream);
    build_prep_a<<<B1_GRID + XPREP_BLKS, 256, 0, stream>>>(eSrc, eDst, cursorB, pairs, x, planeA);

    // ---- stage B: bucket2 || wprep || sums-zero (prep backfills idle CUs) ----
    build_prep_b<<<NBKT + WPREP_BLKS_1K + SUMS_BLKS_1K, 1024, 0, stream>>>(cursorB, pairs, row_ptr, csr, wp, sums);

    // ---- 3 fused layers, ping-pong planes ----
    u16* hin  = planeA;
    u16* hout = planeB;
    for (int l = 0; l < 3; ++l) {
        gin_layer<<<GRID_FUSED, 256, 0, stream>>>(hin, row_ptr, csr,
                                                  Wb + (size_t)(2 * l) * 32768, b1[l],
                                                  Wb + (size_t)(2 * l + 1) * 32768, b2[l],
                                                  hout, (l < 2) ? 1 : 0);
        u16* tmp = hin; hin = hout; hout = tmp;
    }
    // after 3 swaps, final output is in `hin` (= planeB)
    psum_kernel<<<POOL_BLKS, 256, 0, stream>>>(hin, batch, sums);
    pdiv_kernel<<<N_GRAPHS, 128, 0, stream>>>(sums, batch, (float*)d_out);
}